// Round 17
// baseline (98.335 us; speedup 1.0000x reference)
//
#include <hip/hip_runtime.h>

#define EPS 1e-6f
#define J 24
#define NPAIR 12
#define PAIR_STRIDE 28   // v2f per joint-pair block (56 floats, 224 B)

typedef float v2f __attribute__((ext_vector_type(2)));

__device__ __forceinline__ v2f fma2(v2f a, v2f b, v2f c) {
    return __builtin_elementwise_fma(a, b, c);
}
__device__ __forceinline__ v2f max2(v2f a, v2f b) {
    return __builtin_elementwise_max(a, b);
}

// element k of joint j lives at lds[(j>>1)*28 + k].lane(j&1)
//  k 0..11  T rows 0..2
//  k 12..14 tml = T translation - loc    (u = R.p + tml)
//  k 15     f0 = C0*F0 + 0.5
//  k 16..18 cx, cy, cz
//  k 19..21 cxy, cyz, cxz
//  k 22..24 gxx, gyy, gzz
__global__ __launch_bounds__(256, 6) void shcaster_kernel(
    const float* __restrict__ xyz,
    const float* __restrict__ vdir,
    const float* __restrict__ transforms,
    const float* __restrict__ sh_feats,
    const float* __restrict__ locs,
    float* __restrict__ out,
    int n)
{
    __shared__ v2f sj[NPAIR * PAIR_STRIDE];
    const int tid = threadIdx.x;
    const int i = blockIdx.x * blockDim.x + tid;

    // issue point loads early (independent of the fold)
    float px = 0.f, py = 0.f, pz = 0.f, vx = 0.f, vy = 0.f, vz = 0.f;
    if (i < n) {
        px = xyz[3 * i + 0];
        py = xyz[3 * i + 1];
        pz = xyz[3 * i + 2];
        vx = vdir[3 * i + 0];
        vy = vdir[3 * i + 1];
        vz = vdir[3 * i + 2];
    }

    // ---- inline fold: threads 0..23 prepare joint constants ----
    if (tid < J) {
        const int j = tid;
        float F[9];
        #pragma unroll
        for (int k = 0; k < 9; ++k) F[k] = sh_feats[j * 9 + k];

        const float C0  = 0.28209479177387814f;
        const float C1  = 0.4886025119029199f;
        const float C2a = 1.0925484305920792f;

        const float f0  = C0 * F[0] + 0.5f;
        const float cy  = -C1 * F[1];
        const float cz  =  C1 * F[2];
        const float cx  = -C1 * F[3];
        const float cxy =  C2a * F[4];
        const float cyz = -C2a * F[5];
        const float c6  = 0.31539156525252005f * F[6];
        const float cxz = -C2a * F[7];
        const float c8  = 0.5462742152960396f  * F[8];

        float vals[25];
        #pragma unroll
        for (int k = 0; k < 12; ++k) vals[k] = transforms[j * 16 + k];
        vals[12] = vals[3]  - locs[j * 3 + 0];
        vals[13] = vals[7]  - locs[j * 3 + 1];
        vals[14] = vals[11] - locs[j * 3 + 2];
        vals[15] = f0;
        vals[16] = cx;  vals[17] = cy;  vals[18] = cz;
        vals[19] = cxy; vals[20] = cyz; vals[21] = cxz;
        vals[22] = c8 - c6;
        vals[23] = -c6 - c8;
        vals[24] = 2.0f * c6;

        float* base = (float*)&sj[(j >> 1) * PAIR_STRIDE] + (j & 1);
        #pragma unroll
        for (int k = 0; k < 25; ++k) base[2 * k] = vals[k];
    }
    __syncthreads();

    if (i >= n) return;

    const v2f px2 = {px, px};
    const v2f py2 = {py, py};
    const v2f pz2 = {pz, pz};
    const v2f one2  = {1.f, 1.f};
    const v2f zero2 = {0.f, 0.f};

    v2f wsum2 = zero2;
    v2f Ta2[12];
    #pragma unroll
    for (int k = 0; k < 12; ++k) Ta2[k] = zero2;

    #pragma unroll 2
    for (int pp = 0; pp < NPAIR; ++pp) {
        const v2f* s = &sj[pp * PAIR_STRIDE];   // wave-uniform -> LDS broadcast

        // u = R.p + (t - loc)
        const v2f ux = fma2(s[0], px2, fma2(s[1], py2, fma2(s[2],  pz2, s[12])));
        const v2f uy = fma2(s[4], px2, fma2(s[5], py2, fma2(s[6],  pz2, s[13])));
        const v2f uz = fma2(s[8], px2, fma2(s[9], py2, fma2(s[10], pz2, s[14])));

        const v2f xx = ux * ux;
        const v2f yy = uy * uy;
        const v2f zz = uz * uz;
        v2f d2 = (xx + yy) + zz;
        d2 = max2(d2, (v2f){1e-24f, 1e-24f});

        // rsq starts; lin/quad fill its latency
        const v2f inv = {__builtin_amdgcn_rsqf(d2.x), __builtin_amdgcn_rsqf(d2.y)};

        const v2f lin  = fma2(s[16], ux, fma2(s[17], uy, s[18] * uz));
        const v2f quad = fma2(s[19], ux * uy, fma2(s[20], uy * uz, fma2(s[21], ux * uz,
                         fma2(s[22], xx, fma2(s[23], yy, s[24] * zz)))));

        const v2f len = d2 * inv;                 // |u|
        // scaled by d2: R2 = rads*d2 (pre-relu), branch/clamp scale-equivalent
        const v2f R2  = fma2(s[15], d2, fma2(-lin, len, quad));
        const v2f ed2 = d2 * (v2f){EPS, EPS};
        const v2f num = len * d2;

        const v2f rm = max2(R2, ed2);
        const v2f rc = {__builtin_amdgcn_rcpf(rm.x), __builtin_amdgcn_rcpf(rm.y)};
        v2f rel = max2(fma2(-num, rc, one2), zero2);
        rel.x = (R2.x < ed2.x) ? 0.f : rel.x;
        rel.y = (R2.y < ed2.y) ? 0.f : rel.y;

        // wave-uniform skip: all-zero rel pairs contribute nothing (exact)
        if (__ballot((rel.x > 0.f) || (rel.y > 0.f)) != 0ull) {
            wsum2 += rel;
            #pragma unroll
            for (int k = 0; k < 12; ++k) Ta2[k] = fma2(rel, s[k], Ta2[k]);
        }
    }

    const float wsum = wsum2.x + wsum2.y;
    float Ta[12];
    #pragma unroll
    for (int k = 0; k < 12; ++k) Ta[k] = Ta2[k].x + Ta2[k].y;

    const float inv_w = __builtin_amdgcn_rcpf(fmaxf(wsum, EPS));
    const bool valid = wsum > EPS;

    const float axo = fmaf(Ta[0], px, fmaf(Ta[1], py, fmaf(Ta[2],  pz, Ta[3])))  * inv_w;
    const float ayo = fmaf(Ta[4], px, fmaf(Ta[5], py, fmaf(Ta[6],  pz, Ta[7])))  * inv_w;
    const float azo = fmaf(Ta[8], px, fmaf(Ta[9], py, fmaf(Ta[10], pz, Ta[11]))) * inv_w;

    const float qx = px - vx;
    const float qy = py - vy;
    const float qz = pz - vz;
    const float bxo = fmaf(Ta[0], qx, fmaf(Ta[1], qy, fmaf(Ta[2],  qz, Ta[3])))  * inv_w;
    const float byo = fmaf(Ta[4], qx, fmaf(Ta[5], qy, fmaf(Ta[6],  qz, Ta[7])))  * inv_w;
    const float bzo = fmaf(Ta[8], qx, fmaf(Ta[9], qy, fmaf(Ta[10], qz, Ta[11]))) * inv_w;

    const float ox = valid ? axo : px;
    const float oy = valid ? ayo : py;
    const float oz = valid ? azo : pz;
    const float wx = ox - (valid ? bxo : qx);
    const float wy = oy - (valid ? byo : qy);
    const float wz = oz - (valid ? bzo : qz);

    out[3 * i + 0] = ox;
    out[3 * i + 1] = oy;
    out[3 * i + 2] = oz;
    float* out2 = out + (size_t)3 * n;
    out2[3 * i + 0] = wx;
    out2[3 * i + 1] = wy;
    out2[3 * i + 2] = wz;
}

extern "C" void kernel_launch(void* const* d_in, const int* in_sizes, int n_in,
                              void* d_out, int out_size, void* d_ws, size_t ws_size,
                              hipStream_t stream) {
    const int n = (out_size > 0) ? (out_size / 6) : 524288;
    const int big = 3 * n;

    const float* xyz  = nullptr;
    const float* vdir = nullptr;
    const float* trf  = nullptr;
    const float* shf  = nullptr;
    const float* locs = nullptr;
    int bigSeen = 0;
    for (int k = 0; k < n_in; ++k) {
        const int s = in_sizes[k];
        if (s == big) {
            if (bigSeen++ == 0) xyz = (const float*)d_in[k];
            else                vdir = (const float*)d_in[k];
        } else if (s == 384) {
            trf = (const float*)d_in[k];
        } else if (s == 216) {
            shf = (const float*)d_in[k];
        } else if (s == 72) {
            locs = (const float*)d_in[k];
        }
    }
    if (!xyz || !vdir || !trf || !shf || !locs) {
        xyz  = (const float*)d_in[0];
        vdir = (const float*)d_in[1];
        trf  = (const float*)d_in[2];
        shf  = (const float*)d_in[n_in >= 6 ? 4 : 3];
        locs = (const float*)d_in[n_in >= 6 ? 5 : 4];
    }

    float* out = (float*)d_out;
    const int block = 256;
    const int grid = (n + block - 1) / block;
    shcaster_kernel<<<grid, block, 0, stream>>>(xyz, vdir, trf, shf, locs, out, n);
}

// Round 18
// 87.506 us; speedup vs baseline: 1.1237x; 1.1237x over previous
//
#include <hip/hip_runtime.h>

#define EPS 1e-6f
#define J 24
#define NPAIR 12
#define PAIR_STRIDE 56   // floats per joint-pair block (28 v2f, 224 B, 16B-aligned)

typedef float v2f __attribute__((ext_vector_type(2)));

__device__ __forceinline__ v2f fma2(v2f a, v2f b, v2f c) {
    return __builtin_elementwise_fma(a, b, c);
}
__device__ __forceinline__ v2f max2(v2f a, v2f b) {
    return __builtin_elementwise_max(a, b);
}

// ---- setup: fold constants, pair-interleaved SoA in d_ws ----
// element k of joint j: cj[(j>>1)*56 + 2k + (j&1)]
//  k 0..11  T rows 0..2 | k 12..14 tml = t - loc | k 15 f0
//  k 16..18 cx,cy,cz | k 19..21 cxy,cyz,cxz | k 22..24 gxx,gyy,gzz
__global__ void fold_kernel(const float* __restrict__ transforms,
                            const float* __restrict__ sh_feats,
                            const float* __restrict__ locs,
                            float* __restrict__ cj)
{
    const int j = threadIdx.x;
    if (j >= J) return;

    float F[9];
    #pragma unroll
    for (int k = 0; k < 9; ++k) F[k] = sh_feats[j * 9 + k];

    const float C0  = 0.28209479177387814f;
    const float C1  = 0.4886025119029199f;
    const float C2a = 1.0925484305920792f;

    const float f0  = C0 * F[0] + 0.5f;
    const float cy  = -C1 * F[1];
    const float cz  =  C1 * F[2];
    const float cx  = -C1 * F[3];
    const float cxy =  C2a * F[4];
    const float cyz = -C2a * F[5];
    const float c6  = 0.31539156525252005f * F[6];
    const float cxz = -C2a * F[7];
    const float c8  = 0.5462742152960396f  * F[8];

    float vals[25];
    #pragma unroll
    for (int k = 0; k < 12; ++k) vals[k] = transforms[j * 16 + k];
    vals[12] = vals[3]  - locs[j * 3 + 0];
    vals[13] = vals[7]  - locs[j * 3 + 1];
    vals[14] = vals[11] - locs[j * 3 + 2];
    vals[15] = f0;
    vals[16] = cx;  vals[17] = cy;  vals[18] = cz;
    vals[19] = cxy; vals[20] = cyz; vals[21] = cxz;
    vals[22] = c8 - c6;       // gxx
    vals[23] = -c6 - c8;      // gyy
    vals[24] = 2.0f * c6;     // gzz

    float* base = cj + (j >> 1) * PAIR_STRIDE + (j & 1);
    #pragma unroll
    for (int k = 0; k < 25; ++k) base[2 * k] = vals[k];
}

// ---- main: 1 point/thread, 2 joints/iter, no-normalize rads, 8 waves/SIMD ----
__global__ __launch_bounds__(256, 8) void shcaster_kernel(
    const float* __restrict__ xyz,
    const float* __restrict__ vdir,
    const float* __restrict__ cj,
    float* __restrict__ out,
    int n)
{
    const int i = blockIdx.x * blockDim.x + threadIdx.x;
    if (i >= n) return;

    const float px = xyz[3 * i + 0];
    const float py = xyz[3 * i + 1];
    const float pz = xyz[3 * i + 2];
    // vdir loads deferred to epilogue to trim live VGPRs in the K-loop

    const v2f px2 = {px, px};
    const v2f py2 = {py, py};
    const v2f pz2 = {pz, pz};
    const v2f one2  = {1.f, 1.f};
    const v2f zero2 = {0.f, 0.f};
    const v2f eps2  = {EPS, EPS};

    v2f wsum2 = zero2;
    v2f Ta2[12];
    #pragma unroll
    for (int k = 0; k < 12; ++k) Ta2[k] = zero2;

    #pragma unroll 2
    for (int pp = 0; pp < NPAIR; ++pp) {
        const v2f* s = (const v2f*)(cj + pp * PAIR_STRIDE);  // wave-uniform s_load

        // u = R.p + (t - loc)
        const v2f ux = fma2(s[0], px2, fma2(s[1], py2, fma2(s[2],  pz2, s[12])));
        const v2f uy = fma2(s[4], px2, fma2(s[5], py2, fma2(s[6],  pz2, s[13])));
        const v2f uz = fma2(s[8], px2, fma2(s[9], py2, fma2(s[10], pz2, s[14])));

        const v2f xx = ux * ux;
        const v2f yy = uy * uy;
        const v2f zz = uz * uz;
        v2f d2 = (xx + yy) + zz;
        d2 = max2(d2, (v2f){1e-24f, 1e-24f});

        // rsq kicks off; lin/quad fill its latency
        const v2f inv = {__builtin_amdgcn_rsqf(d2.x), __builtin_amdgcn_rsqf(d2.y)};

        const v2f lin  = fma2(s[16], ux, fma2(s[17], uy, s[18] * uz));
        const v2f quad = fma2(s[19], ux * uy, fma2(s[20], uy * uz, fma2(s[21], ux * uz,
                         fma2(s[22], xx, fma2(s[23], yy, s[24] * zz)))));

        const v2f len  = d2 * inv;        // = |u|
        const v2f inv2 = inv * inv;       // = 1/d2

        // rads = f0 - lin*inv + quad*inv2   (vd = -u flips the linear term)
        v2f rads = fma2(quad, inv2, s[15]);
        rads = fma2(-lin, inv, rads);
        rads = max2(rads, zero2);

        const v2f rm = max2(rads, eps2);
        const v2f rc = {__builtin_amdgcn_rcpf(rm.x), __builtin_amdgcn_rcpf(rm.y)};
        v2f rel = max2(fma2(-len, rc, one2), zero2);
        rel.x = (rads.x < EPS) ? 0.f : rel.x;
        rel.y = (rads.y < EPS) ? 0.f : rel.y;

        wsum2 += rel;
        #pragma unroll
        for (int k = 0; k < 12; ++k) Ta2[k] = fma2(rel, s[k], Ta2[k]);
    }

    const float wsum = wsum2.x + wsum2.y;
    float Ta[12];
    #pragma unroll
    for (int k = 0; k < 12; ++k) Ta[k] = Ta2[k].x + Ta2[k].y;

    const float vx = vdir[3 * i + 0];
    const float vy = vdir[3 * i + 1];
    const float vz = vdir[3 * i + 2];

    const float inv_w = __builtin_amdgcn_rcpf(fmaxf(wsum, EPS));
    const bool valid = wsum > EPS;

    const float axo = fmaf(Ta[0], px, fmaf(Ta[1], py, fmaf(Ta[2],  pz, Ta[3])))  * inv_w;
    const float ayo = fmaf(Ta[4], px, fmaf(Ta[5], py, fmaf(Ta[6],  pz, Ta[7])))  * inv_w;
    const float azo = fmaf(Ta[8], px, fmaf(Ta[9], py, fmaf(Ta[10], pz, Ta[11]))) * inv_w;

    const float qx = px - vx;
    const float qy = py - vy;
    const float qz = pz - vz;
    const float bxo = fmaf(Ta[0], qx, fmaf(Ta[1], qy, fmaf(Ta[2],  qz, Ta[3])))  * inv_w;
    const float byo = fmaf(Ta[4], qx, fmaf(Ta[5], qy, fmaf(Ta[6],  qz, Ta[7])))  * inv_w;
    const float bzo = fmaf(Ta[8], qx, fmaf(Ta[9], qy, fmaf(Ta[10], qz, Ta[11]))) * inv_w;

    const float ox = valid ? axo : px;
    const float oy = valid ? ayo : py;
    const float oz = valid ? azo : pz;
    const float wx = ox - (valid ? bxo : qx);
    const float wy = oy - (valid ? byo : qy);
    const float wz = oz - (valid ? bzo : qz);

    out[3 * i + 0] = ox;
    out[3 * i + 1] = oy;
    out[3 * i + 2] = oz;
    float* out2 = out + (size_t)3 * n;
    out2[3 * i + 0] = wx;
    out2[3 * i + 1] = wy;
    out2[3 * i + 2] = wz;
}

extern "C" void kernel_launch(void* const* d_in, const int* in_sizes, int n_in,
                              void* d_out, int out_size, void* d_ws, size_t ws_size,
                              hipStream_t stream) {
    const int n = (out_size > 0) ? (out_size / 6) : 524288;
    const int big = 3 * n;

    const float* xyz  = nullptr;
    const float* vdir = nullptr;
    const float* trf  = nullptr;
    const float* shf  = nullptr;
    const float* locs = nullptr;
    int bigSeen = 0;
    for (int k = 0; k < n_in; ++k) {
        const int s = in_sizes[k];
        if (s == big) {
            if (bigSeen++ == 0) xyz = (const float*)d_in[k];
            else                vdir = (const float*)d_in[k];
        } else if (s == 384) {
            trf = (const float*)d_in[k];
        } else if (s == 216) {
            shf = (const float*)d_in[k];
        } else if (s == 72) {
            locs = (const float*)d_in[k];
        }
    }
    if (!xyz || !vdir || !trf || !shf || !locs) {
        xyz  = (const float*)d_in[0];
        vdir = (const float*)d_in[1];
        trf  = (const float*)d_in[2];
        shf  = (const float*)d_in[n_in >= 6 ? 4 : 3];
        locs = (const float*)d_in[n_in >= 6 ? 5 : 4];
    }

    float* cj = (float*)d_ws;          // 12 pairs * 56 floats = 2688 B
    float* out = (float*)d_out;

    fold_kernel<<<1, 64, 0, stream>>>(trf, shf, locs, cj);

    const int block = 256;
    const int grid = (n + block - 1) / block;
    shcaster_kernel<<<grid, block, 0, stream>>>(xyz, vdir, cj, out, n);
}